// Round 1
// baseline (395.801 us; speedup 1.0000x reference)
//
#include <hip/hip_runtime.h>
#include <math.h>

#define N_G   64
#define M_N   32
#define NM    2048     // N_G * M_N
#define FEAT  256
#define POSD  6
#define D     262
#define D2    524
#define MSG   128
#define G3    786
#define G3P   788      // padded stride (multiple of 4)
#define NCLS  7

// ---- workspace float offsets ----
#define O_H       0u         // 2048*262 = 536576
#define O_WTPROJ  536576u    // 262*524  = 137288
#define O_MSGT    673872u    // 262*128  = 33536
#define O_IHT     707408u    // 128*788  = 100864
#define O_HHT     808272u    // 262*788  = 206456
#define O_RO1T    1014736u   // 262*128  = 33536
#define O_ATT     1048272u   // 2048*32  = 65536
#define O_MSGBUF  1113808u   // 2048*128 = 262144
#define O_MV      1375952u   // 2048*128 = 262144
#define O_GX      1638096u   // 2048*786 = 1609728
#define O_GH      3247824u   // 2048*786 = 1609728
#define O_PROJ    O_GX       // proj (2048*524) reuses gx/gh space; consumed before round 0
// total: 4,857,552 floats = 19.4 MB

// ---------------------------------------------------------------------------
// prep: build nf (= initial h) and transposed weight copies (coalesced GEMM B)
// ---------------------------------------------------------------------------
__global__ void prep_kernel(const float* __restrict__ nodes, const float* __restrict__ pos,
                            const float* __restrict__ w1, const float* __restrict__ msg_w,
                            const float* __restrict__ w_ih, const float* __restrict__ w_hh,
                            const float* __restrict__ ro_w1, float* __restrict__ ws)
{
    const int T_H    = NM * D;
    const int T_W1   = D * D2;
    const int T_MSGT = D * MSG;
    const int T_IHT  = MSG * G3P;
    const int T_HHT  = D * G3P;
    const int T_RO1  = D * MSG;
    const int TOTAL  = T_H + T_W1 + T_MSGT + T_IHT + T_HHT + T_RO1;
    for (int i = blockIdx.x * blockDim.x + threadIdx.x; i < TOTAL;
         i += gridDim.x * blockDim.x) {
        int idx = i;
        if (idx < T_H) {
            int n = idx / D, c = idx % D;
            ws[O_H + idx] = (c < FEAT) ? nodes[n * FEAT + c] : pos[n * POSD + (c - FEAT)];
            continue;
        }
        idx -= T_H;
        if (idx < T_W1) {
            // wtproj[c][o]: o<262 -> w1[o][c] (pa half), else w1[o-262][262+c] (pb half)
            int c = idx / D2, o = idx % D2;
            float v = (o < D) ? w1[o * D2 + c] : w1[(o - D) * D2 + D + c];
            ws[O_WTPROJ + idx] = v;
            continue;
        }
        idx -= T_W1;
        if (idx < T_MSGT) {
            int c = idx / MSG, k = idx % MSG;
            ws[O_MSGT + idx] = msg_w[k * D + c];
            continue;
        }
        idx -= T_MSGT;
        if (idx < T_IHT) {
            int c = idx / G3P, g = idx % G3P;
            ws[O_IHT + idx] = (g < G3) ? w_ih[g * MSG + c] : 0.f;
            continue;
        }
        idx -= T_IHT;
        if (idx < T_HHT) {
            int c = idx / G3P, g = idx % G3P;
            ws[O_HHT + idx] = (g < G3) ? w_hh[g * D + c] : 0.f;
            continue;
        }
        idx -= T_HHT;
        {
            int c = idx / MSG, k = idx % MSG;
            ws[O_RO1T + idx] = ro_w1[k * D + c];
        }
    }
}

// ---------------------------------------------------------------------------
// tiled fp32 GEMM: C[m][n] = act( sum_k A[m][k] * B[k][n] + bias[n] )
// BM=BN=64, BK=16, 256 threads, 4x4 per thread. M (=2048) divisible by 64.
// ---------------------------------------------------------------------------
#define BM 64
#define BN 64
#define BK 16

__global__ __launch_bounds__(256) void gemm_kernel(
    const float* __restrict__ A, int lda,
    const float* __restrict__ B, int ldb,
    const float* __restrict__ bias,
    float* __restrict__ C, int ldc,
    int K, int N, int act)
{
    __shared__ float As[BK][BM + 4];
    __shared__ float Bs[BK][BN];
    const int tid = threadIdx.x;
    const int n0 = blockIdx.x * BN;
    const int m0 = blockIdx.y * BM;
    const int tr = tid >> 4, tc = tid & 15;
    const int a_m = tid >> 2;            // 0..63
    const int a_k0 = (tid & 3) * 4;      // 0,4,8,12
    const int b_k = tid >> 4;            // 0..15
    const int b_n0 = (tid & 15) * 4;     // 0..60
    float acc[4][4] = {};
    for (int k0 = 0; k0 < K; k0 += BK) {
#pragma unroll
        for (int u = 0; u < 4; ++u) {
            int k = a_k0 + u;
            int kg = k0 + k;
            As[k][a_m] = (kg < K) ? A[(m0 + a_m) * lda + kg] : 0.f;
        }
#pragma unroll
        for (int u = 0; u < 4; ++u) {
            int n = b_n0 + u;
            int kg = k0 + b_k;
            int ng = n0 + n;
            Bs[b_k][n] = (kg < K && ng < N) ? B[kg * ldb + ng] : 0.f;
        }
        __syncthreads();
#pragma unroll
        for (int kk = 0; kk < BK; ++kk) {
            float4 a4 = *(const float4*)&As[kk][tr * 4];
            float4 b4 = *(const float4*)&Bs[kk][tc * 4];
            float av[4] = {a4.x, a4.y, a4.z, a4.w};
            float bv[4] = {b4.x, b4.y, b4.z, b4.w};
#pragma unroll
            for (int r = 0; r < 4; ++r)
#pragma unroll
                for (int c = 0; c < 4; ++c)
                    acc[r][c] = fmaf(av[r], bv[c], acc[r][c]);
        }
        __syncthreads();
    }
#pragma unroll
    for (int r = 0; r < 4; ++r) {
        int m = m0 + tr * 4 + r;
#pragma unroll
        for (int c = 0; c < 4; ++c) {
            int n = n0 + tc * 4 + c;
            if (n < N) {
                float v = acc[r][c] + (bias ? bias[n] : 0.f);
                if (act == 1) v = fmaxf(v, 0.f);
                C[m * ldc + n] = v;
            }
        }
    }
}

// ---------------------------------------------------------------------------
// attention: attmat[b,i,j] = sigmoid( sum_d relu(pair*(pa_i[d]+pb_j[d]) + b1[d]) * w2[d] + b2 )
// block per (b,i); 256 threads = 32 j-groups of 8 lanes
// ---------------------------------------------------------------------------
__global__ __launch_bounds__(256) void att_kernel(
    const float* __restrict__ proj, const float* __restrict__ b1,
    const float* __restrict__ w2, const float* __restrict__ b2,
    const int* __restrict__ num_rec,
    float* __restrict__ att_out, float* __restrict__ att_m)
{
    __shared__ float paL[D], b1L[D], w2L[D];
    const int n = blockIdx.x;            // receiver node flat id
    const int b = n >> 5, i = n & 31;
    const int nrec = num_rec[b];
    const int t = threadIdx.x;
    const bool valid_i = i < nrec;
    for (int d = t; d < D; d += 256) {
        paL[d] = proj[n * D2 + d];
        b1L[d] = b1[d];
        w2L[d] = w2[d];
    }
    __syncthreads();
    const int j = t >> 3, c8 = t & 7;
    const bool valid_j = j < nrec;
    const float sel = (valid_i && valid_j) ? 1.f : 0.f;
    const float* pbrow = proj + (b * 32 + j) * D2 + D;
    float partial = 0.f;
    for (int d = c8; d < D; d += 8) {
        float v = sel * (paL[d] + pbrow[d]) + b1L[d];
        partial += fmaxf(v, 0.f) * w2L[d];
    }
    partial += __shfl_down(partial, 4, 8);
    partial += __shfl_down(partial, 2, 8);
    partial += __shfl_down(partial, 1, 8);
    if (c8 == 0) {
        float s = partial + b2[0];
        float a = 1.f / (1.f + expf(-s));
        att_out[n * 32 + j] = a;                 // full attmat output (pre-mask)
        att_m[n * 32 + j] = valid_j ? a : 0.f;   // sender-masked version for mixing
    }
}

// ---------------------------------------------------------------------------
// m_v[b,i,k] = sum_w att_m[b,i,w] * msg[b,w,k]   (block per node, thread per k)
// ---------------------------------------------------------------------------
__global__ __launch_bounds__(128) void mix_kernel(
    const float* __restrict__ att_m, const float* __restrict__ msg,
    float* __restrict__ mv)
{
    __shared__ float aL[32];
    const int n = blockIdx.x;
    const int b = n >> 5;
    const int t = threadIdx.x;
    if (t < 32) aL[t] = att_m[n * 32 + t];
    __syncthreads();
    const float* mb = msg + (b * 32) * MSG + t;
    float acc = 0.f;
#pragma unroll
    for (int w = 0; w < 32; ++w)
        acc = fmaf(aL[w], mb[w * MSG], acc);
    mv[n * MSG + t] = acc;
}

// ---------------------------------------------------------------------------
// GRU gate elementwise: h = ((1-z)*c + z*h) * valid
// ---------------------------------------------------------------------------
__global__ void gru_kernel(const float* __restrict__ gx, const float* __restrict__ gh,
                           const int* __restrict__ num_rec, float* __restrict__ h)
{
    int idx = blockIdx.x * blockDim.x + threadIdx.x;
    if (idx >= NM * D) return;
    int n = idx / D, d = idx % D;
    float xr = gx[n * G3 + d], xz = gx[n * G3 + D + d], xn = gx[n * G3 + 2 * D + d];
    float hr = gh[n * G3 + d], hz = gh[n * G3 + D + d], hn = gh[n * G3 + 2 * D + d];
    float r = 1.f / (1.f + expf(-(xr + hr)));
    float z = 1.f / (1.f + expf(-(xz + hz)));
    float c = tanhf(xn + r * hn);
    float ho = h[idx];
    float hv = (1.f - z) * c + z * ho;
    int i = n & 31, b = n >> 5;
    if (i >= num_rec[b]) hv = 0.f;
    h[idx] = hv;
}

// ---------------------------------------------------------------------------
// final: pred[n,q] = (sum_k hid[n,k]*ro_w2[q,k] + ro_b2[q]) * valid
// ---------------------------------------------------------------------------
__global__ __launch_bounds__(64) void final_kernel(
    const float* __restrict__ hid, const float* __restrict__ ro_w2,
    const float* __restrict__ ro_b2, const int* __restrict__ num_rec,
    float* __restrict__ pred)
{
    const int n = blockIdx.x;
    const int t = threadIdx.x;
    const int q = t >> 3, c8 = t & 7;
    float partial = 0.f;
    if (q < NCLS) {
        const float* hrow = hid + n * MSG;
        const float* wrow = ro_w2 + q * MSG;
        for (int k = c8; k < MSG; k += 8)
            partial = fmaf(hrow[k], wrow[k], partial);
    }
    partial += __shfl_down(partial, 4, 8);
    partial += __shfl_down(partial, 2, 8);
    partial += __shfl_down(partial, 1, 8);
    if (c8 == 0 && q < NCLS) {
        float v = partial + ro_b2[q];
        int i = n & 31, b = n >> 5;
        if (i >= num_rec[b]) v = 0.f;
        pred[n * NCLS + q] = v;
    }
}

// ---------------------------------------------------------------------------
extern "C" void kernel_launch(void* const* d_in, const int* in_sizes, int n_in,
                              void* d_out, int out_size, void* d_ws, size_t ws_size,
                              hipStream_t stream)
{
    const float* nodes = (const float*)d_in[0];
    const float* pos   = (const float*)d_in[1];
    const int*   nrec  = (const int*)d_in[2];
    const float* w1    = (const float*)d_in[3];   // link_w1 (262,524)
    const float* b1    = (const float*)d_in[4];   // link_b1 (262)
    const float* w2    = (const float*)d_in[5];   // link_w2 (262)
    const float* b2    = (const float*)d_in[6];   // link_b2 ()
    const float* msg_w = (const float*)d_in[7];   // (128,262)
    const float* msg_b = (const float*)d_in[8];   // (128)
    const float* w_ih  = (const float*)d_in[9];   // (786,128)
    const float* w_hh  = (const float*)d_in[10];  // (786,262)
    const float* b_ih  = (const float*)d_in[11];  // (786)
    const float* b_hh  = (const float*)d_in[12];  // (786)
    const float* ro_w1 = (const float*)d_in[13];  // (128,262)
    const float* ro_b1 = (const float*)d_in[14];  // (128)
    const float* ro_w2 = (const float*)d_in[15];  // (7,128)
    const float* ro_b2 = (const float*)d_in[16];  // (7)
    float* ws   = (float*)d_ws;
    float* pred = (float*)d_out;                  // (64,32,7) = 14336
    float* attout = pred + NM * NCLS;             // (64,32,32) = 65536

    // 1) nf (=h0) + transposed weights
    prep_kernel<<<1024, 256, 0, stream>>>(nodes, pos, w1, msg_w, w_ih, w_hh, ro_w1, ws);

    // 2) proj = nf @ [W1a^T | W1b^T]  -> (2048, 524)
    gemm_kernel<<<dim3((D2 + BN - 1) / BN, NM / BM), 256, 0, stream>>>(
        ws + O_H, D, ws + O_WTPROJ, D2, nullptr, ws + O_PROJ, D2, D, D2, 0);

    // 3) attention matrix (output) + sender-masked att_m
    att_kernel<<<NM, 256, 0, stream>>>(ws + O_PROJ, b1, w2, b2, nrec, attout, ws + O_ATT);

    // 4) two message-passing rounds
    for (int round = 0; round < 2; ++round) {
        gemm_kernel<<<dim3(MSG / BN, NM / BM), 256, 0, stream>>>(
            ws + O_H, D, ws + O_MSGT, MSG, msg_b, ws + O_MSGBUF, MSG, D, MSG, 0);
        mix_kernel<<<NM, 128, 0, stream>>>(ws + O_ATT, ws + O_MSGBUF, ws + O_MV);
        gemm_kernel<<<dim3((G3 + BN - 1) / BN, NM / BM), 256, 0, stream>>>(
            ws + O_MV, MSG, ws + O_IHT, G3P, b_ih, ws + O_GX, G3, MSG, G3, 0);
        gemm_kernel<<<dim3((G3 + BN - 1) / BN, NM / BM), 256, 0, stream>>>(
            ws + O_H, D, ws + O_HHT, G3P, b_hh, ws + O_GH, G3, D, G3, 0);
        gru_kernel<<<(NM * D + 255) / 256, 256, 0, stream>>>(ws + O_GX, ws + O_GH, nrec, ws + O_H);
    }

    // 5) readout
    gemm_kernel<<<dim3(MSG / BN, NM / BM), 256, 0, stream>>>(
        ws + O_H, D, ws + O_RO1T, MSG, ro_b1, ws + O_MSGBUF, MSG, D, MSG, 1);
    final_kernel<<<NM, 64, 0, stream>>>(ws + O_MSGBUF, ro_w2, ro_b2, nrec, pred);
}

// Round 2
// 172.851 us; speedup vs baseline: 2.2898x; 2.2898x over previous
//
#include <hip/hip_runtime.h>
#include <math.h>

#define N_G   64
#define M_N   32
#define NM    2048
#define FEAT  256
#define POSD  6
#define D     262
#define D2    524
#define MSG   128
#define G3    786
#define NCLS  7

#define KA    416      // padded K of concat A: [mv(128) | h(262) | pad(26)]
#define KH    288      // padded K over h (262 -> 288)
#define N1    1472     // G1 output cols padded: gh(786) + msg(128) + proj(524) = 1438 -> 1472
#define N1B   960      // round-1 G1: gh+msg = 914 -> 960
#define N2    832      // G2 output cols: 786 -> 832
#define C_MSG 786      // msg cols start in g1out
#define C_PRJ 914      // proj cols start in g1out

// ---- workspace float offsets ----
#define O_HF   0u          // 2048*262 fp32 h state            = 536576
#define O_ABF  536576u     // 2048*416 bf16 concat A           = 425984 floats
#define O_WG1  962560u     // 1472*288 bf16                    = 211968 floats
#define O_WG2  1174528u    // 832*128 bf16                     = 53248 floats
#define O_WRO  1227776u    // 128*288 bf16                     = 18432 floats
#define O_ATT  1246208u    // 2048*32 fp32 masked att          = 65536
#define O_G1   1311744u    // 2048*1472 fp32                   = 3014656
#define O_G2   4326400u    // 2048*832 fp32 (reused for RO out)= 1703936
// total ~6.03M floats = 24.1 MB

typedef __attribute__((ext_vector_type(8))) short short8;
typedef __attribute__((ext_vector_type(4))) float floatx4;

__device__ __forceinline__ short f2bf(float f) {
    union { float f; unsigned u; } v; v.f = f;
    unsigned r = v.u + 0x7FFF + ((v.u >> 16) & 1);   // RNE
    return (short)(r >> 16);
}
__device__ __forceinline__ float sigf(float x) { return 1.f / (1.f + expf(-x)); }

// ---------------------------------------------------------------------------
// prep: fp32 h0, bf16 concat-A, bf16 transposed/padded weight blocks
// ---------------------------------------------------------------------------
__global__ void prep_kernel(const float* __restrict__ nodes, const float* __restrict__ pos,
                            const float* __restrict__ w1, const float* __restrict__ msg_w,
                            const float* __restrict__ w_ih, const float* __restrict__ w_hh,
                            const float* __restrict__ ro_w1, float* __restrict__ ws)
{
    float* hf = ws + O_HF;
    short* abf = (short*)(ws + O_ABF);
    short* wg1 = (short*)(ws + O_WG1);
    short* wg2 = (short*)(ws + O_WG2);
    short* wro = (short*)(ws + O_WRO);
    const int T_HF  = NM * D;
    const int T_ABF = NM * KA;
    const int T_WG1 = N1 * KH;
    const int T_WG2 = N2 * MSG;
    const int T_WRO = MSG * KH;
    const int TOTAL = T_HF + T_ABF + T_WG1 + T_WG2 + T_WRO;
    for (int i = blockIdx.x * blockDim.x + threadIdx.x; i < TOTAL;
         i += gridDim.x * blockDim.x) {
        int idx = i;
        if (idx < T_HF) {
            int n = idx / D, c = idx % D;
            hf[idx] = (c < FEAT) ? nodes[n * FEAT + c] : pos[n * POSD + (c - FEAT)];
            continue;
        }
        idx -= T_HF;
        if (idx < T_ABF) {
            int m = idx / KA, c = idx % KA;
            float v = 0.f;
            if (c >= 128 && c < 128 + D) {
                int d = c - 128;
                v = (d < FEAT) ? nodes[m * FEAT + d] : pos[m * POSD + (d - FEAT)];
            }
            abf[idx] = f2bf(v);
            continue;
        }
        idx -= T_ABF;
        if (idx < T_WG1) {
            int n = idx / KH, k = idx % KH;
            float v = 0.f;
            if (k < D) {
                if (n < G3)            v = w_hh[n * D + k];
                else if (n < C_PRJ)    v = msg_w[(n - C_MSG) * D + k];
                else if (n < C_PRJ + D2) {
                    int o = n - C_PRJ;
                    v = (o < D) ? w1[o * D2 + k] : w1[(o - D) * D2 + D + k];
                }
            }
            wg1[idx] = f2bf(v);
            continue;
        }
        idx -= T_WG1;
        if (idx < T_WG2) {
            int n = idx / MSG, k = idx % MSG;
            wg2[idx] = f2bf(n < G3 ? w_ih[n * MSG + k] : 0.f);
            continue;
        }
        idx -= T_WG2;
        {
            int n = idx / KH, k = idx % KH;
            wro[idx] = f2bf(k < D ? ro_w1[n * D + k] : 0.f);
        }
    }
}

// ---------------------------------------------------------------------------
// bf16 MFMA GEMM: C[m][n] = act( A[m][:] . B[n][:] + bias[n] )
// A: [M][lda] bf16 row-major, B: [N][ldb] bf16 (B^T layout). block 64x64, 4 waves.
// ---------------------------------------------------------------------------
__global__ __launch_bounds__(256) void mfma_gemm(
    const short* __restrict__ A, int lda,
    const short* __restrict__ B, int ldb,
    const float* __restrict__ bias,
    float* __restrict__ C, int ldc,
    int K, int act)
{
    const int wave = threadIdx.x >> 6;
    const int lane = threadIdx.x & 63;
    const int wm = (wave >> 1) * 32;
    const int wn = (wave & 1) * 32;
    const int m0 = blockIdx.y * 64 + wm;
    const int n0 = blockIdx.x * 64 + wn;
    const int quad = lane >> 4;      // 0..3
    const int lrow = lane & 15;
    floatx4 acc00 = {}, acc01 = {}, acc10 = {}, acc11 = {};
    const short* Ab = A + (size_t)(m0 + lrow) * lda + quad * 8;
    const short* Bb = B + (size_t)(n0 + lrow) * ldb + quad * 8;
    for (int k0 = 0; k0 < K; k0 += 32) {
        short8 a0 = *(const short8*)(Ab + k0);
        short8 a1 = *(const short8*)(Ab + (size_t)16 * lda + k0);
        short8 b0 = *(const short8*)(Bb + k0);
        short8 b1 = *(const short8*)(Bb + (size_t)16 * ldb + k0);
        acc00 = __builtin_amdgcn_mfma_f32_16x16x32_bf16(a0, b0, acc00, 0, 0, 0);
        acc01 = __builtin_amdgcn_mfma_f32_16x16x32_bf16(a0, b1, acc01, 0, 0, 0);
        acc10 = __builtin_amdgcn_mfma_f32_16x16x32_bf16(a1, b0, acc10, 0, 0, 0);
        acc11 = __builtin_amdgcn_mfma_f32_16x16x32_bf16(a1, b1, acc11, 0, 0, 0);
    }
    floatx4 av[2][2] = {{acc00, acc01}, {acc10, acc11}};
#pragma unroll
    for (int i = 0; i < 2; ++i)
#pragma unroll
        for (int j = 0; j < 2; ++j) {
            int col = n0 + j * 16 + lrow;
            float bv = bias ? bias[col] : 0.f;
#pragma unroll
            for (int r = 0; r < 4; ++r) {
                int row = m0 + i * 16 + quad * 4 + r;
                float v = av[i][j][r] + bv;
                if (act) v = fmaxf(v, 0.f);
                C[(size_t)row * ldc + col] = v;
            }
        }
}

// ---------------------------------------------------------------------------
// attention from proj columns of g1out
// ---------------------------------------------------------------------------
__global__ __launch_bounds__(256) void att_kernel(
    const float* __restrict__ g1, const float* __restrict__ b1,
    const float* __restrict__ w2, const float* __restrict__ b2,
    const int* __restrict__ num_rec,
    float* __restrict__ att_out, float* __restrict__ att_m)
{
    __shared__ float paL[D], b1L[D], w2L[D];
    const int n = blockIdx.x;
    const int b = n >> 5, i = n & 31;
    const int nrec = num_rec[b];
    const int t = threadIdx.x;
    const bool valid_i = i < nrec;
    for (int d = t; d < D; d += 256) {
        paL[d] = g1[(size_t)n * N1 + C_PRJ + d];
        b1L[d] = b1[d];
        w2L[d] = w2[d];
    }
    __syncthreads();
    const int j = t >> 3, c8 = t & 7;
    const bool valid_j = j < nrec;
    const float sel = (valid_i && valid_j) ? 1.f : 0.f;
    const float* pbrow = g1 + (size_t)(b * 32 + j) * N1 + C_PRJ + D;
    float partial = 0.f;
    for (int d = c8; d < D; d += 8) {
        float v = sel * (paL[d] + pbrow[d]) + b1L[d];
        partial += fmaxf(v, 0.f) * w2L[d];
    }
    partial += __shfl_down(partial, 4, 8);
    partial += __shfl_down(partial, 2, 8);
    partial += __shfl_down(partial, 1, 8);
    if (c8 == 0) {
        float a = sigf(partial + b2[0]);
        att_out[n * 32 + j] = a;
        att_m[n * 32 + j] = valid_j ? a : 0.f;
    }
}

// ---------------------------------------------------------------------------
// mv[b,i,k] = sum_w att_m[b,i,w] * (msg[b,w,k]+msg_b[k]) -> bf16 into A cols 0..128
// ---------------------------------------------------------------------------
__global__ __launch_bounds__(128) void mix_kernel(
    const float* __restrict__ att_m, const float* __restrict__ g1,
    const float* __restrict__ msg_b, short* __restrict__ abf)
{
    __shared__ float aL[32];
    const int n = blockIdx.x;
    const int b = n >> 5;
    const int t = threadIdx.x;
    if (t < 32) aL[t] = att_m[n * 32 + t];
    __syncthreads();
    const float* mb = g1 + (size_t)(b * 32) * N1 + C_MSG + t;
    const float bias = msg_b[t];
    float acc = 0.f;
#pragma unroll
    for (int w = 0; w < 32; ++w)
        acc = fmaf(aL[w], mb[(size_t)w * N1] + bias, acc);
    abf[(size_t)n * KA + t] = f2bf(acc);
}

// ---------------------------------------------------------------------------
// GRU elementwise; writes fp32 h and bf16 h into A cols 128..390
// ---------------------------------------------------------------------------
__global__ void gru_kernel(const float* __restrict__ g2, const float* __restrict__ g1,
                           const float* __restrict__ bih, const float* __restrict__ bhh,
                           const int* __restrict__ num_rec,
                           float* __restrict__ hf, short* __restrict__ abf)
{
    int idx = blockIdx.x * blockDim.x + threadIdx.x;
    if (idx >= NM * D) return;
    int n = idx / D, d = idx % D;
    const float* g1r = g1 + (size_t)n * N1;
    const float* g2r = g2 + (size_t)n * N2;
    float r = sigf(g2r[d] + bih[d] + g1r[d] + bhh[d]);
    float z = sigf(g2r[D + d] + bih[D + d] + g1r[D + d] + bhh[D + d]);
    float c = tanhf(g2r[2 * D + d] + bih[2 * D + d] + r * (g1r[2 * D + d] + bhh[2 * D + d]));
    float hv = (1.f - z) * c + z * hf[idx];
    int i = n & 31, b = n >> 5;
    if (i >= num_rec[b]) hv = 0.f;
    hf[idx] = hv;
    abf[(size_t)n * KA + 128 + d] = f2bf(hv);
}

// ---------------------------------------------------------------------------
// final: pred[n,q] = (hid[n,:] . ro_w2[q,:] + ro_b2[q]) * valid
// ---------------------------------------------------------------------------
__global__ __launch_bounds__(64) void final_kernel(
    const float* __restrict__ hid, const float* __restrict__ ro_w2,
    const float* __restrict__ ro_b2, const int* __restrict__ num_rec,
    float* __restrict__ pred)
{
    const int n = blockIdx.x;
    const int t = threadIdx.x;
    const int q = t >> 3, c8 = t & 7;
    float partial = 0.f;
    if (q < NCLS) {
        const float* hrow = hid + (size_t)n * MSG;
        const float* wrow = ro_w2 + q * MSG;
        for (int k = c8; k < MSG; k += 8)
            partial = fmaf(hrow[k], wrow[k], partial);
    }
    partial += __shfl_down(partial, 4, 8);
    partial += __shfl_down(partial, 2, 8);
    partial += __shfl_down(partial, 1, 8);
    if (c8 == 0 && q < NCLS) {
        float v = partial + ro_b2[q];
        int i = n & 31, b = n >> 5;
        if (i >= num_rec[b]) v = 0.f;
        pred[n * NCLS + q] = v;
    }
}

// ---------------------------------------------------------------------------
extern "C" void kernel_launch(void* const* d_in, const int* in_sizes, int n_in,
                              void* d_out, int out_size, void* d_ws, size_t ws_size,
                              hipStream_t stream)
{
    const float* nodes = (const float*)d_in[0];
    const float* pos   = (const float*)d_in[1];
    const int*   nrec  = (const int*)d_in[2];
    const float* w1    = (const float*)d_in[3];
    const float* b1    = (const float*)d_in[4];
    const float* w2    = (const float*)d_in[5];
    const float* b2    = (const float*)d_in[6];
    const float* msg_w = (const float*)d_in[7];
    const float* msg_b = (const float*)d_in[8];
    const float* w_ih  = (const float*)d_in[9];
    const float* w_hh  = (const float*)d_in[10];
    const float* b_ih  = (const float*)d_in[11];
    const float* b_hh  = (const float*)d_in[12];
    const float* ro_w1 = (const float*)d_in[13];
    const float* ro_b1 = (const float*)d_in[14];
    const float* ro_w2 = (const float*)d_in[15];
    const float* ro_b2 = (const float*)d_in[16];
    float* ws   = (float*)d_ws;
    float* pred = (float*)d_out;
    float* attout = pred + NM * NCLS;

    float* hf  = ws + O_HF;
    short* abf = (short*)(ws + O_ABF);
    short* wg1 = (short*)(ws + O_WG1);
    short* wg2 = (short*)(ws + O_WG2);
    short* wro = (short*)(ws + O_WRO);
    float* att = ws + O_ATT;
    float* g1  = ws + O_G1;
    float* g2  = ws + O_G2;

    prep_kernel<<<512, 256, 0, stream>>>(nodes, pos, w1, msg_w, w_ih, w_hh, ro_w1, ws);

    // round 0 G1: [gh | msg | proj] = h0 @ WG1^T   (N=1472, K=288)
    mfma_gemm<<<dim3(N1 / 64, NM / 64), 256, 0, stream>>>(
        abf + 128, KA, wg1, KH, nullptr, g1, N1, KH, 0);
    att_kernel<<<NM, 256, 0, stream>>>(g1, b1, w2, b2, nrec, attout, att);
    mix_kernel<<<NM, 128, 0, stream>>>(att, g1, msg_b, abf);
    mfma_gemm<<<dim3(N2 / 64, NM / 64), 256, 0, stream>>>(
        abf, KA, wg2, MSG, nullptr, g2, N2, MSG, 0);
    gru_kernel<<<(NM * D + 255) / 256, 256, 0, stream>>>(g2, g1, b_ih, b_hh, nrec, hf, abf);

    // round 1 G1: [gh | msg] only (N=960)
    mfma_gemm<<<dim3(N1B / 64, NM / 64), 256, 0, stream>>>(
        abf + 128, KA, wg1, KH, nullptr, g1, N1, KH, 0);
    mix_kernel<<<NM, 128, 0, stream>>>(att, g1, msg_b, abf);
    mfma_gemm<<<dim3(N2 / 64, NM / 64), 256, 0, stream>>>(
        abf, KA, wg2, MSG, nullptr, g2, N2, MSG, 0);
    gru_kernel<<<(NM * D + 255) / 256, 256, 0, stream>>>(g2, g1, b_ih, b_hh, nrec, hf, abf);

    // readout: relu(h @ ro_w1^T + ro_b1) -> g2 (ldc=128), then final
    mfma_gemm<<<dim3(MSG / 64, NM / 64), 256, 0, stream>>>(
        abf + 128, KA, wro, KH, ro_b1, g2, MSG, KH, 1);
    final_kernel<<<NM, 64, 0, stream>>>(g2, ro_w2, ro_b2, nrec, pred);
}